// Round 1
// 494.375 us; speedup vs baseline: 1.0149x; 1.0149x over previous
//
#include <hip/hip_runtime.h>
#include <math.h>

#define BDIM 128
#define SDIM 512
#define KDIM 4
#define DDIM 300
#define CNUM 20
#define TSB  64                  // s-values per block (was 32)
#define NTILE (SDIM / TSB)       // 8 tiles
#define SG   4                   // s-groups per block
#define SPG  (TSB / SG)          // 16 s per group
#define NPART (NTILE * SG)       // 32 partials per b (was 64)
#define NQ   (DDIM / 4)          // 75 float4 per row

// Kernel 1: each block = one (tile,b). 320 threads.
// Staging: ALL 320 threads gather (256 do NX/EW->edge_w, 64 do X->node_w),
// doubling in-flight random gathers per block vs the 160-of-320 layout.
// One barrier per block. Streaming gathers are non-temporal so the 400MB
// edge_w lines don't evict the L2-resident 12MB embedding table.
__global__ __launch_bounds__(320) void gnn_accum(
    const int* __restrict__ X, const int* __restrict__ NX,
    const int* __restrict__ EW, const float* __restrict__ emb,
    const float* __restrict__ edge_w, const float* __restrict__ node_w,
    float* __restrict__ part)
{
    const int tile = blockIdx.x;
    const int b    = blockIdx.y;
    const int s0   = tile * TSB;
    const int t    = threadIdx.x;

    __shared__ int   s_nx[TSB * KDIM];
    __shared__ float s_ew[TSB * KDIM];
    __shared__ int   s_x[TSB];
    __shared__ float s_nw[TSB];

    if (t < TSB * KDIM) {                       // 256 threads: one (s,k) each
        const int gi = (b * SDIM + s0) * KDIM + t;
        s_nx[t] = __builtin_nontemporal_load(&NX[gi]);
        const int e = __builtin_nontemporal_load(&EW[gi]);
        s_ew[t] = __builtin_nontemporal_load(&edge_w[e]);   // random 4B in 400MB
    } else {                                    // 64 threads: one s each
        const int j = t - TSB * KDIM;
        const int x = __builtin_nontemporal_load(&X[b * SDIM + s0 + j]);
        s_x[j]  = x;
        s_nw[j] = node_w[x];                    // 40KB table, keep cached
    }
    __syncthreads();

    const int sgrp = t / 80;
    const int dq   = t % 80;
    if (dq < NQ) {
        const float4* __restrict__ emb4 = (const float4*)emb;
        float4 acc = make_float4(0.f, 0.f, 0.f, 0.f);
        #pragma unroll 4
        for (int i = 0; i < SPG; ++i) {
            const int j  = sgrp * SPG + i;          // s within tile
            const int n0 = s_nx[j * 4 + 0];
            const int n1 = s_nx[j * 4 + 1];
            const int n2 = s_nx[j * 4 + 2];
            const int n3 = s_nx[j * 4 + 3];
            const float w0 = s_ew[j * 4 + 0], w1 = s_ew[j * 4 + 1];
            const float w2 = s_ew[j * 4 + 2], w3 = s_ew[j * 4 + 3];
            const float4 r0 = emb4[n0 * NQ + dq];
            const float4 r1 = emb4[n1 * NQ + dq];
            const float4 r2 = emb4[n2 * NQ + dq];
            const float4 r3 = emb4[n3 * NQ + dq];
            const float4 rx = emb4[s_x[j] * NQ + dq];
            const float nw = s_nw[j];
            const float mw = 1.f - nw;
            acc.x += mw * (w0 * r0.x + w1 * r1.x + w2 * r2.x + w3 * r3.x) + nw * rx.x;
            acc.y += mw * (w0 * r0.y + w1 * r1.y + w2 * r2.y + w3 * r3.y) + nw * rx.y;
            acc.z += mw * (w0 * r0.z + w1 * r1.z + w2 * r2.z + w3 * r3.z) + nw * rx.z;
            acc.w += mw * (w0 * r0.w + w1 * r1.w + w2 * r2.w + w3 * r3.w) + nw * rx.w;
        }
        float4* part4 = (float4*)part;
        part4[((tile * SG + sgrp) * BDIM + b) * NQ + dq] = acc;
    }
}

// Kernel 2: reduce NPART partials, fc (20x300) + bias, relu, softmax. Block/b.
__global__ __launch_bounds__(320) void gnn_head(
    const float* __restrict__ part, const float* __restrict__ fc_w,
    const float* __restrict__ fc_b, float* __restrict__ out)
{
    const int b = blockIdx.x;
    const int t = threadIdx.x;

    __shared__ float sf[DDIM];
    __shared__ float slog[CNUM];

    if (t < DDIM) {
        float f = 0.f;
        #pragma unroll 8
        for (int p = 0; p < NPART; ++p)
            f += part[(p * BDIM + b) * DDIM + t];
        sf[t] = f;
    }
    __syncthreads();

    const int c    = t >> 4;     // 16 threads per class
    const int lane = t & 15;
    float sum = 0.f;
    if (c < CNUM) {
        for (int d = lane; d < DDIM; d += 16)
            sum += sf[d] * fc_w[c * DDIM + d];
    }
    #pragma unroll
    for (int off = 8; off > 0; off >>= 1)
        sum += __shfl_down(sum, off, 16);
    if (c < CNUM && lane == 0)
        slog[c] = sum + fc_b[c];
    __syncthreads();

    if (t == 0) {
        float r[CNUM];
        float m = 0.f;                        // relu floor
        #pragma unroll
        for (int i = 0; i < CNUM; ++i) {
            float v = slog[i];
            r[i] = v > 0.f ? v : 0.f;
            if (r[i] > m) m = r[i];
        }
        float s = 0.f;
        #pragma unroll
        for (int i = 0; i < CNUM; ++i) { r[i] = expf(r[i] - m); s += r[i]; }
        const float inv = 1.f / s;
        #pragma unroll
        for (int i = 0; i < CNUM; ++i) out[b * CNUM + i] = r[i] * inv;
    }
}

extern "C" void kernel_launch(void* const* d_in, const int* in_sizes, int n_in,
                              void* d_out, int out_size, void* d_ws, size_t ws_size,
                              hipStream_t stream) {
    const int*   X        = (const int*)  d_in[0];
    const int*   NX       = (const int*)  d_in[1];
    const int*   EW       = (const int*)  d_in[2];
    const float* node_emb = (const float*)d_in[3];
    const float* edge_w   = (const float*)d_in[4];
    const float* node_w   = (const float*)d_in[5];
    const float* fc_w     = (const float*)d_in[6];
    const float* fc_b     = (const float*)d_in[7];
    float* out  = (float*)d_out;
    float* part = (float*)d_ws;            // NPART*B*D floats = 4.9 MB

    dim3 grid1(NTILE, BDIM);
    gnn_accum<<<grid1, 320, 0, stream>>>(X, NX, EW, node_emb, edge_w, node_w, part);
    gnn_head<<<BDIM, 320, 0, stream>>>(part, fc_w, fc_b, out);
}